// Round 2
// baseline (258.745 us; speedup 1.0000x reference)
//
#include <hip/hip_runtime.h>

// B=4, N=4096, E=2048, C=64.  Single fp32 pass over H (fused into the edge
// GEMM, which also emits bit-packed H), then a barrier-free bit-driven node
// GEMM.
//  k_transform: xtT[b][o][n] bf16 (2 MB)
//  k_edge:  p_he[ks] += xtT * H  (cndmask fp32->bf16) AND
//           Hbits[b][wd][n] (word-major) via __ballot AND deg_e_part.
//           K-split x4 over N. ONLY reader of fp32 H (134 MB). BW-bound.
//  k_henorm: combine/deg_e -> heT bf16 (1 MB)
//  k_node:  out = (H * heT)/deg_n + bias, FULL-E accumulation. NO LDS, NO
//           barriers: A = Hbits u64 expanded in regs, B = heT 16B fragments
//           direct from global (L2-resident, 64B-contiguous per quad-group).
//           deg_n via popcount; divide+bias fused in epilogue.
#define B_ 4
#define N_ 4096
#define E_ 2048

typedef __attribute__((ext_vector_type(8))) short short8;   // 8 bf16
typedef __attribute__((ext_vector_type(4))) float float4v;  // MFMA C/D

// round-to-nearest-even f32 -> bf16 bits
static __device__ __forceinline__ unsigned short f2bf(float f) {
  union { float f; unsigned int u; } v; v.f = f;
  unsigned int r = (v.u + 0x7FFFu + ((v.u >> 16) & 1u)) >> 16;
  return (unsigned short)r;
}

// expand 8 H-bits -> 8 bf16 values {0.0, 1.0}
static __device__ __forceinline__ short8 expand8(unsigned int by) {
  short8 r;
#pragma unroll
  for (int j = 0; j < 8; ++j)
    r[j] = (short)(((by >> j) & 1u) ? 0x3F80 : 0);
  return r;
}

static __device__ __forceinline__ void stage16(const void* g, void* l) {
  __builtin_amdgcn_global_load_lds(
      (const __attribute__((address_space(1))) unsigned int*)g,
      (__attribute__((address_space(3))) unsigned int*)l, 16, 0, 0);
}

// ---------------------------------------------------------------------------
// K1: xtT[b][o][n] = bf16( sum_k x[b][n][k] * theta[k][o] )   (transposed)
// ---------------------------------------------------------------------------
__global__ __launch_bounds__(256) void k_transform(
    const float* __restrict__ x, const float* __restrict__ theta,
    unsigned short* __restrict__ xtT) {
  __shared__ unsigned short ldsT[64][72];
  int t = threadIdx.x;
  int nt = blockIdx.x & 63, b = blockIdx.x >> 6;
  int n0 = nt * 64;
  int o = t & 63, nq = t >> 6;
#pragma unroll 4
  for (int i = 0; i < 16; ++i) {
    int n = n0 + nq * 16 + i;
    const float* xr = x + ((size_t)(b * N_ + n) << 6);
    float acc = 0.f;
#pragma unroll
    for (int k = 0; k < 64; ++k) acc += xr[k] * theta[k * 64 + o];
    ldsT[o][nq * 16 + i] = f2bf(acc);
  }
  __syncthreads();
  int orow = t >> 2, c = (t & 3) * 16;
  unsigned short* dst = xtT + ((size_t)(b * 64 + orow) << 12) + n0 + c;
  *(uint4*)dst = *(const uint4*)&ldsT[orow][c];
  *(uint4*)(dst + 8) = *(const uint4*)&ldsT[orow][c + 8];
}

// ---------------------------------------------------------------------------
// K2 (fused edge GEMM + bit-pack): for K-chunk ks (1024 n each, x4):
//   p_he[ks][b][o][e]    = sum_{n chunk} xtT[o][n] * H[n][e]
//   deg_e_part[ks][b][e] = sum_{n chunk} H[n][e]
//   Hbits[b][et][n chunk] = ballot-packed bits (word-major)
// grid 512 = ks(4) x et(32) x b(4); block 64o x 64e, BK=64, 16 iters.
// ---------------------------------------------------------------------------
__global__ __launch_bounds__(256) void k_edge(
    const unsigned short* __restrict__ xtT, const float* __restrict__ H,
    float* __restrict__ p_he, float* __restrict__ deg_e_part,
    unsigned long long* __restrict__ Hbits) {
  __shared__ unsigned short ldsA[4096];     // [o-row][k=n] 64x64, swizzled
  __shared__ unsigned short ldsB[64 * 72];  // [e-row][n] 64x72 padded
  __shared__ float ldsDe[64];
  __shared__ unsigned long long ldsW[1024];  // packed words for this n-chunk
  int t = threadIdx.x;
  int ks = blockIdx.x & 3, et = (blockIdx.x >> 2) & 31, b = blockIdx.x >> 7;
  int e0 = et * 64;
  int w = t >> 6, lane = t & 63, quad = lane >> 4, m15 = lane & 15;
  if (t < 64) ldsDe[t] = 0.f;

  int i0 = w * 128 + lane, i1 = i0 + 64;
  int row0 = i0 >> 3, cc0 = (i0 & 7) ^ (row0 & 7);
  int row1 = i1 >> 3, cc1 = (i1 & 7) ^ (row1 & 7);
  int gOff0 = row0 * 4096 + cc0 * 8;
  int gOff1 = row1 * 4096 + cc1 * 8;
  char* lA = (char*)ldsA; char* lB = (char*)ldsB;
  int lOff0 = i0 * 16, lOff1 = i1 * 16;

  const unsigned short* gA = xtT + ((size_t)b << 18) + ks * 1024;
  const float* gH = H + ((size_t)(b * N_ + ks * 1024 + w * 16)) * E_ + e0 + lane;

  int xr = m15 & 7;
  int aBase = (w * 16 + m15) * 128;
  int fs0 = (quad ^ xr) * 16, fs1 = ((4 + quad) ^ xr) * 16;
  int bw = lane * 144 + w * 32;

  float de = 0.f;
  float4v acc[4];
#pragma unroll
  for (int ct = 0; ct < 4; ++ct) acc[ct] = (float4v){0.f, 0.f, 0.f, 0.f};

  for (int kt = 0; kt < 16; ++kt) {
    float hv[16];
#pragma unroll
    for (int i = 0; i < 16; ++i) hv[i] = gH[(size_t)i * E_];
    // bit-pack: lane = e offset -> one 64-bit word per n-row
#pragma unroll
    for (int i = 0; i < 16; ++i) {
      unsigned long long m = __ballot(hv[i] != 0.0f);
      if (lane == 0) ldsW[kt * 64 + w * 16 + i] = m;
    }
#pragma unroll
    for (int i = 0; i < 16; ++i) de += hv[i];
    // H is exactly {0.0,1.0}: bf16 is a cndmask on the compare the ballot
    // already needs (f2bf RNE bit-math was ~5 VALU ops/element).
    short8 pa, pb;
#pragma unroll
    for (int i = 0; i < 8; ++i)
      pa[i] = (hv[i] != 0.0f) ? (short)0x3F80 : (short)0;
#pragma unroll
    for (int i = 0; i < 8; ++i)
      pb[i] = (hv[8 + i] != 0.0f) ? (short)0x3F80 : (short)0;
    *(short8*)(lB + bw) = pa;
    *(short8*)(lB + bw + 16) = pb;
    stage16(gA + gOff0, lA + lOff0);
    stage16(gA + gOff1, lA + lOff1);
    __syncthreads();
#pragma unroll
    for (int s = 0; s < 2; ++s) {
      int fo = s ? fs1 : fs0;
      short8 a = *(const short8*)(lA + aBase + fo);
#pragma unroll
      for (int ct = 0; ct < 4; ++ct) {
        short8 bb =
            *(const short8*)(lB + (ct * 16 + m15) * 144 + s * 64 + quad * 16);
        acc[ct] = __builtin_amdgcn_mfma_f32_16x16x32_bf16(a, bb, acc[ct], 0, 0, 0);
      }
    }
    __syncthreads();
    gA += 64;
    gH += (size_t)64 * E_;
  }
  atomicAdd(&ldsDe[lane], de);
  __syncthreads();
  if (t < 64) deg_e_part[ks * (B_ * E_) + b * E_ + e0 + t] = ldsDe[t];
  // coalesced Hbits write: [b][et][n], n-chunk = ks*1024..+1024 (8 KB/block)
  unsigned long long* wdst =
      Hbits + (((size_t)(b * 32 + et)) << 12) + ks * 1024 + t * 4;
  wdst[0] = ldsW[t * 4 + 0];
  wdst[1] = ldsW[t * 4 + 1];
  wdst[2] = ldsW[t * 4 + 2];
  wdst[3] = ldsW[t * 4 + 3];
  float* dst = p_he + (size_t)ks * (B_ * 64 * E_);
#pragma unroll
  for (int ct = 0; ct < 4; ++ct)
#pragma unroll
    for (int r = 0; r < 4; ++r) {
      int oo = w * 16 + quad * 4 + r;
      dst[((size_t)(b * 64 + oo)) * E_ + e0 + ct * 16 + m15] = acc[ct][r];
    }
}

// ---------------------------------------------------------------------------
// K3: heT[b][o][e] = bf16( (sum_ks p_he[ks]) / (sum_ks deg_e_part[ks]) )
// ---------------------------------------------------------------------------
__global__ __launch_bounds__(256) void k_henorm(
    const float* __restrict__ p_he, const float* __restrict__ deg_e_part,
    unsigned short* __restrict__ heT) {
  int idx = (blockIdx.x * 256 + threadIdx.x) * 4;  // over B*64*E = 524288
  int e = idx & (E_ - 1);
  int b = idx >> 17;
  float4 s = *(const float4*)(p_he + idx);
  float4 d = *(const float4*)(deg_e_part + b * E_ + e);
#pragma unroll
  for (int k = 1; k < 4; ++k) {
    float4 sk = *(const float4*)(p_he + (size_t)k * (B_ * 64 * E_) + idx);
    float4 dk = *(const float4*)(deg_e_part + k * (B_ * E_) + b * E_ + e);
    s.x += sk.x; s.y += sk.y; s.z += sk.z; s.w += sk.w;
    d.x += dk.x; d.y += dk.y; d.z += dk.z; d.w += dk.w;
  }
  unsigned int lo = (unsigned int)f2bf(s.x / d.x) |
                    ((unsigned int)f2bf(s.y / d.y) << 16);
  unsigned int hi = (unsigned int)f2bf(s.z / d.z) |
                    ((unsigned int)f2bf(s.w / d.w) << 16);
  uint2 u; u.x = lo; u.y = hi;
  *(uint2*)(heT + idx) = u;
}

// ---------------------------------------------------------------------------
// K4 (node GEMM + normalize + bias, barrier-free):
//   out[b][n][o] = (sum_e H[n][e]*heT[o][e]) / deg_n[n] + bias[o]
// grid 512 = mt(64) x ot(2) x b(4); tile 64n x 32o, full E (32 k-steps).
// A = Hbits[b][wd][n] u64 (L2-hot) expanded in regs;
// B = heT 16B fragments DIRECT from global: chunk (s*4+quad)*8 within the
//     kt*64 e-window (same e<->k-slot mapping the staged version used, with
//     the XOR swizzle algebra folded out). 4 quads of a ct-group read 64
//     contiguous bytes -> L2-friendly. No LDS, no __syncthreads: compiler
//     pipelines loads across the unrolled kt loop.
// deg_n via popcount; divide+bias fused in epilogue.
// ---------------------------------------------------------------------------
__global__ __launch_bounds__(256) void k_node(
    const unsigned long long* __restrict__ Hbits,
    const unsigned short* __restrict__ heT,
    const float* __restrict__ bias, float* __restrict__ out) {
  int t = threadIdx.x;
  int mt = blockIdx.x & 63, ot = (blockIdx.x >> 6) & 1, b = blockIdx.x >> 7;
  int n0 = mt * 64, o0 = ot * 32;
  int w = t >> 6, lane = t & 63, quad = lane >> 4, m15 = lane & 15;

  int nl = n0 + w * 16 + m15;
  const unsigned long long* gAb = Hbits + (((size_t)b * 32) << 12) + nl;
  // B rows for this lane: o = o0 + ct*16 + m15 (ct = 0,1)
  const unsigned short* gB0 = heT + (((size_t)(b * 64 + o0 + m15)) << 11);
  const unsigned short* gB1 = gB0 + (16 << 11);

  float4v acc[2];
  acc[0] = (float4v){0.f, 0.f, 0.f, 0.f};
  acc[1] = (float4v){0.f, 0.f, 0.f, 0.f};

  unsigned int dcnt = 0;
#pragma unroll 4
  for (int kt = 0; kt < 32; ++kt) {
    unsigned long long ua = gAb[(size_t)kt << 12];
    dcnt += (unsigned int)__popcll(ua);
#pragma unroll
    for (int s = 0; s < 2; ++s) {
      int eo = kt * 64 + (s * 4 + quad) * 8;  // e-offset of this k-chunk
      short8 a = expand8((unsigned int)(ua >> ((s * 4 + quad) << 3)) & 0xFFu);
      short8 b0 = *(const short8*)(gB0 + eo);
      short8 b1 = *(const short8*)(gB1 + eo);
      acc[0] = __builtin_amdgcn_mfma_f32_16x16x32_bf16(a, b0, acc[0], 0, 0, 0);
      acc[1] = __builtin_amdgcn_mfma_f32_16x16x32_bf16(a, b1, acc[1], 0, 0, 0);
    }
  }

  float dn = (float)dcnt;  // same for all quads of a given (w, m15)
  float bv0 = bias[o0 + m15];
  float bv1 = bias[o0 + 16 + m15];
  float* dst = out + (((size_t)(b * N_ + n0)) << 6) + o0;
#pragma unroll
  for (int r = 0; r < 4; ++r) {
    float inv = 1.0f / __shfl(dn, quad * 4 + r, 16);
    int rr = w * 16 + quad * 4 + r;
    dst[((size_t)rr << 6) + m15] = acc[0][r] * inv + bv0;
    dst[((size_t)rr << 6) + 16 + m15] = acc[1][r] * inv + bv1;
  }
}

extern "C" void kernel_launch(void* const* d_in, const int* in_sizes, int n_in,
                              void* d_out, int out_size, void* d_ws, size_t ws_size,
                              hipStream_t stream) {
  const float* x     = (const float*)d_in[0];
  const float* H     = (const float*)d_in[1];
  const float* theta = (const float*)d_in[2];
  const float* bias  = (const float*)d_in[3];

  // ws (bytes): xtT 2MB | p_he 8MB | heT 1MB | deg_e_part 128KB | Hbits 4MB
  //             (~15.1 MB total)
  char* ws = (char*)d_ws;
  unsigned short* xtT       = (unsigned short*)ws;
  float* p_he               = (float*)(ws + 2097152);
  unsigned short* heT       = (unsigned short*)(ws + 10485760);
  float* deg_e_part         = (float*)(ws + 11534336);
  unsigned long long* Hbits = (unsigned long long*)(ws + 11665408);

  k_transform<<<256, 256, 0, stream>>>(x, theta, xtT);
  k_edge<<<512, 256, 0, stream>>>(xtT, H, p_he, deg_e_part, Hbits);
  k_henorm<<<512, 256, 0, stream>>>(p_he, deg_e_part, heT);
  k_node<<<512, 256, 0, stream>>>(Hbits, heT, bias, (float*)d_out);
}

// Round 3
// 249.558 us; speedup vs baseline: 1.0368x; 1.0368x over previous
//
#include <hip/hip_runtime.h>

// B=4, N=4096, E=2048, C=64.  Single fp32 pass over H (fused into the edge
// GEMM, which also emits bit-packed H), then a fused bit-driven node GEMM.
//  k_transform: xtT[b][o][n] bf16 (2 MB)
//  k_edge:  p_he[ks] += xtT * H  (cndmask fp32->bf16) AND
//           Hbits[b][wd][n] (word-major) via __ballot AND deg_e_part.
//           K-split x8 over N (4 blocks/CU). ONLY reader of fp32 H (134 MB).
//  k_henorm: combine/deg_e -> heT bf16 (1 MB)
//  k_node:  out = (H * heT)/deg_n + bias, FULL-E accumulation. 32n x 32o
//           tile, grid 1024 -> 4 blocks/CU (16 waves/CU) so the per-k-step
//           barrier vmcnt-drain overlaps with 3 other resident blocks.
//           A = Hbits u64 expanded in regs, B = heT staged via double-
//           buffered global_load_lds; deg_n via popcount in-kernel.
#define B_ 4
#define N_ 4096
#define E_ 2048

typedef __attribute__((ext_vector_type(8))) short short8;   // 8 bf16
typedef __attribute__((ext_vector_type(4))) float float4v;  // MFMA C/D

// round-to-nearest-even f32 -> bf16 bits
static __device__ __forceinline__ unsigned short f2bf(float f) {
  union { float f; unsigned int u; } v; v.f = f;
  unsigned int r = (v.u + 0x7FFFu + ((v.u >> 16) & 1u)) >> 16;
  return (unsigned short)r;
}

// expand 8 H-bits -> 8 bf16 values {0.0, 1.0}
static __device__ __forceinline__ short8 expand8(unsigned int by) {
  short8 r;
#pragma unroll
  for (int j = 0; j < 8; ++j)
    r[j] = (short)(((by >> j) & 1u) ? 0x3F80 : 0);
  return r;
}

static __device__ __forceinline__ void stage16(const void* g, void* l) {
  __builtin_amdgcn_global_load_lds(
      (const __attribute__((address_space(1))) unsigned int*)g,
      (__attribute__((address_space(3))) unsigned int*)l, 16, 0, 0);
}

// ---------------------------------------------------------------------------
// K1: xtT[b][o][n] = bf16( sum_k x[b][n][k] * theta[k][o] )   (transposed)
// ---------------------------------------------------------------------------
__global__ __launch_bounds__(256) void k_transform(
    const float* __restrict__ x, const float* __restrict__ theta,
    unsigned short* __restrict__ xtT) {
  __shared__ unsigned short ldsT[64][72];
  int t = threadIdx.x;
  int nt = blockIdx.x & 63, b = blockIdx.x >> 6;
  int n0 = nt * 64;
  int o = t & 63, nq = t >> 6;
#pragma unroll 4
  for (int i = 0; i < 16; ++i) {
    int n = n0 + nq * 16 + i;
    const float* xr = x + ((size_t)(b * N_ + n) << 6);
    float acc = 0.f;
#pragma unroll
    for (int k = 0; k < 64; ++k) acc += xr[k] * theta[k * 64 + o];
    ldsT[o][nq * 16 + i] = f2bf(acc);
  }
  __syncthreads();
  int orow = t >> 2, c = (t & 3) * 16;
  unsigned short* dst = xtT + ((size_t)(b * 64 + orow) << 12) + n0 + c;
  *(uint4*)dst = *(const uint4*)&ldsT[orow][c];
  *(uint4*)(dst + 8) = *(const uint4*)&ldsT[orow][c + 8];
}

// ---------------------------------------------------------------------------
// K2 (fused edge GEMM + bit-pack): for K-chunk ks (512 n each, x8):
//   p_he[ks][b][o][e]    = sum_{n chunk} xtT[o][n] * H[n][e]
//   deg_e_part[ks][b][e] = sum_{n chunk} H[n][e]
//   Hbits[b][et][n chunk] = ballot-packed bits (word-major)
// grid 1024 = ks(8) x et(32) x b(4); block 64o x 64e, BK=64, 8 iters.
// ---------------------------------------------------------------------------
__global__ __launch_bounds__(256) void k_edge(
    const unsigned short* __restrict__ xtT, const float* __restrict__ H,
    float* __restrict__ p_he, float* __restrict__ deg_e_part,
    unsigned long long* __restrict__ Hbits) {
  __shared__ unsigned short ldsA[4096];     // [o-row][k=n] 64x64, swizzled
  __shared__ unsigned short ldsB[64 * 72];  // [e-row][n] 64x72 padded
  __shared__ float ldsDe[64];
  __shared__ unsigned long long ldsW[512];  // packed words for this n-chunk
  int t = threadIdx.x;
  int ks = blockIdx.x & 7, et = (blockIdx.x >> 3) & 31, b = blockIdx.x >> 8;
  int e0 = et * 64;
  int w = t >> 6, lane = t & 63, quad = lane >> 4, m15 = lane & 15;
  if (t < 64) ldsDe[t] = 0.f;

  int i0 = w * 128 + lane, i1 = i0 + 64;
  int row0 = i0 >> 3, cc0 = (i0 & 7) ^ (row0 & 7);
  int row1 = i1 >> 3, cc1 = (i1 & 7) ^ (row1 & 7);
  int gOff0 = row0 * 4096 + cc0 * 8;
  int gOff1 = row1 * 4096 + cc1 * 8;
  char* lA = (char*)ldsA; char* lB = (char*)ldsB;
  int lOff0 = i0 * 16, lOff1 = i1 * 16;

  const unsigned short* gA = xtT + ((size_t)b << 18) + ks * 512;
  const float* gH = H + ((size_t)(b * N_ + ks * 512 + w * 16)) * E_ + e0 + lane;

  int xr = m15 & 7;
  int aBase = (w * 16 + m15) * 128;
  int fs0 = (quad ^ xr) * 16, fs1 = ((4 + quad) ^ xr) * 16;
  int bw = lane * 144 + w * 32;

  float de = 0.f;
  float4v acc[4];
#pragma unroll
  for (int ct = 0; ct < 4; ++ct) acc[ct] = (float4v){0.f, 0.f, 0.f, 0.f};

  for (int kt = 0; kt < 8; ++kt) {
    float hv[16];
#pragma unroll
    for (int i = 0; i < 16; ++i) hv[i] = gH[(size_t)i * E_];
    // bit-pack: lane = e offset -> one 64-bit word per n-row
#pragma unroll
    for (int i = 0; i < 16; ++i) {
      unsigned long long m = __ballot(hv[i] != 0.0f);
      if (lane == 0) ldsW[kt * 64 + w * 16 + i] = m;
    }
#pragma unroll
    for (int i = 0; i < 16; ++i) de += hv[i];
    // H is exactly {0.0,1.0}: bf16 is a cndmask on the compare the ballot
    // already needs (f2bf RNE bit-math was ~5 VALU ops/element).
    short8 pa, pb;
#pragma unroll
    for (int i = 0; i < 8; ++i)
      pa[i] = (hv[i] != 0.0f) ? (short)0x3F80 : (short)0;
#pragma unroll
    for (int i = 0; i < 8; ++i)
      pb[i] = (hv[8 + i] != 0.0f) ? (short)0x3F80 : (short)0;
    *(short8*)(lB + bw) = pa;
    *(short8*)(lB + bw + 16) = pb;
    stage16(gA + gOff0, lA + lOff0);
    stage16(gA + gOff1, lA + lOff1);
    __syncthreads();
#pragma unroll
    for (int s = 0; s < 2; ++s) {
      int fo = s ? fs1 : fs0;
      short8 a = *(const short8*)(lA + aBase + fo);
#pragma unroll
      for (int ct = 0; ct < 4; ++ct) {
        short8 bb =
            *(const short8*)(lB + (ct * 16 + m15) * 144 + s * 64 + quad * 16);
        acc[ct] = __builtin_amdgcn_mfma_f32_16x16x32_bf16(a, bb, acc[ct], 0, 0, 0);
      }
    }
    __syncthreads();
    gA += 64;
    gH += (size_t)64 * E_;
  }
  atomicAdd(&ldsDe[lane], de);
  __syncthreads();
  if (t < 64) deg_e_part[ks * (B_ * E_) + b * E_ + e0 + t] = ldsDe[t];
  // coalesced Hbits write: [b][et][n], n-chunk = ks*512..+512 (4 KB/block)
  unsigned long long* wdst =
      Hbits + (((size_t)(b * 32 + et)) << 12) + ks * 512 + t * 2;
  wdst[0] = ldsW[t * 2 + 0];
  wdst[1] = ldsW[t * 2 + 1];
  float* dst = p_he + (size_t)ks * (B_ * 64 * E_);
#pragma unroll
  for (int ct = 0; ct < 4; ++ct)
#pragma unroll
    for (int r = 0; r < 4; ++r) {
      int oo = w * 16 + quad * 4 + r;
      dst[((size_t)(b * 64 + oo)) * E_ + e0 + ct * 16 + m15] = acc[ct][r];
    }
}

// ---------------------------------------------------------------------------
// K3: heT[b][o][e] = bf16( (sum_ks p_he[ks]) / (sum_ks deg_e_part[ks]) )
// ---------------------------------------------------------------------------
__global__ __launch_bounds__(256) void k_henorm(
    const float* __restrict__ p_he, const float* __restrict__ deg_e_part,
    unsigned short* __restrict__ heT) {
  int idx = (blockIdx.x * 256 + threadIdx.x) * 4;  // over B*64*E = 524288
  int e = idx & (E_ - 1);
  int b = idx >> 17;
  float4 s = *(const float4*)(p_he + idx);
  float4 d = *(const float4*)(deg_e_part + b * E_ + e);
#pragma unroll
  for (int k = 1; k < 8; ++k) {
    float4 sk = *(const float4*)(p_he + (size_t)k * (B_ * 64 * E_) + idx);
    float4 dk = *(const float4*)(deg_e_part + k * (B_ * E_) + b * E_ + e);
    s.x += sk.x; s.y += sk.y; s.z += sk.z; s.w += sk.w;
    d.x += dk.x; d.y += dk.y; d.z += dk.z; d.w += dk.w;
  }
  unsigned int lo = (unsigned int)f2bf(s.x / d.x) |
                    ((unsigned int)f2bf(s.y / d.y) << 16);
  unsigned int hi = (unsigned int)f2bf(s.z / d.z) |
                    ((unsigned int)f2bf(s.w / d.w) << 16);
  uint2 u; u.x = lo; u.y = hi;
  *(uint2*)(heT + idx) = u;
}

// ---------------------------------------------------------------------------
// K4 (fused node GEMM + normalize + bias):
//   out[b][n][o] = (sum_e H[n][e]*heT[o][e]) / deg_n[n] + bias[o]
// grid 1024 = mt(128) x ot(2) x b(4); tile 32n x 32o, full E (32 k-steps).
// 4 blocks/CU, 16 waves/CU: the per-step barrier's vmcnt drain overlaps
// with 3 other resident blocks' compute.
// A = Hbits[b][wd][n] u64 (wave reads 128B contiguous), prefetched 1 ahead;
// B = heT staged via global_load_lds, 2-deep double-buffered.
// Per wave: 16n x 16o quadrant (w&1 = n-half, w>>1 = o-half), 2 MFMA/step.
// deg_n via popcount of the same words; divide+bias fused in epilogue.
// ---------------------------------------------------------------------------
__global__ __launch_bounds__(256) void k_node(
    const unsigned long long* __restrict__ Hbits,
    const unsigned short* __restrict__ heT,
    const float* __restrict__ bias, float* __restrict__ out) {
  __shared__ unsigned short ldsB[2][2048];  // [buf][32 o x 64 e] swizzled
  int t = threadIdx.x;
  int mt = blockIdx.x & 127, ot = (blockIdx.x >> 7) & 1, b = blockIdx.x >> 8;
  int n0 = mt * 32, o0 = ot * 32;
  int w = t >> 6, lane = t & 63, quad = lane >> 4, m15 = lane & 15;
  int wn = w & 1, wo = w >> 1;  // wave's n-half / o-half of the 32x32 tile

  // staging: 32 o-rows x 64 e (128 B/row = 8 segs), 1 stage16/thread/step
  int row = t >> 3, seg = t & 7;
  int cc = seg ^ (row & 7);  // pre-swizzled global source, linear LDS dest
  const unsigned short* gB =
      heT + (((size_t)(b * 64 + o0 + row)) << 11) + cc * 8;
  char* lB = (char*)ldsB;
  int lOff = t * 16;

  int nl = n0 + wn * 16 + m15;
  const unsigned long long* gAb = Hbits + (((size_t)b * 32) << 12) + nl;

  int xr = m15 & 7;
  int fs0 = (quad ^ xr) * 16, fs1 = ((4 + quad) ^ xr) * 16;
  int bRow = (wo * 16 + m15) * 128;  // byte row of this wave's B fragment

  float4v acc = (float4v){0.f, 0.f, 0.f, 0.f};

  unsigned int dcnt = 0;
  unsigned long long ua = gAb[0];
  stage16(gB, lB + lOff);  // buf0 <- e-chunk 0
  __syncthreads();

  for (int kt = 0; kt < 32; ++kt) {
    int cur = kt & 1;
    if (kt < 31) {
      stage16(gB + (kt + 1) * 64, lB + (cur ^ 1) * 4096 + lOff);
    }
    unsigned long long va = 0;
    if (kt < 31) va = gAb[(size_t)(kt + 1) << 12];  // prefetch next word
    dcnt += (unsigned int)__popcll(ua);
#pragma unroll
    for (int s = 0; s < 2; ++s) {
      int fo = s ? fs1 : fs0;
      short8 a = expand8((unsigned int)(ua >> ((s * 4 + quad) << 3)) & 0xFFu);
      short8 bb = *(const short8*)(lB + cur * 4096 + bRow + fo);
      acc = __builtin_amdgcn_mfma_f32_16x16x32_bf16(a, bb, acc, 0, 0, 0);
    }
    ua = va;
    __syncthreads();  // buf swap safe; other 3 blocks/CU hide the drain
  }

  float dn = (float)dcnt;  // same for all quads of a given (w, m15)
  float bv = bias[o0 + wo * 16 + m15];
  float* dst = out + (((size_t)(b * N_ + n0)) << 6) + o0 + wo * 16;
#pragma unroll
  for (int r = 0; r < 4; ++r) {
    float inv = 1.0f / __shfl(dn, quad * 4 + r, 16);
    int rr = wn * 16 + quad * 4 + r;
    dst[((size_t)rr << 6) + m15] = acc[r] * inv + bv;
  }
}

extern "C" void kernel_launch(void* const* d_in, const int* in_sizes, int n_in,
                              void* d_out, int out_size, void* d_ws, size_t ws_size,
                              hipStream_t stream) {
  const float* x     = (const float*)d_in[0];
  const float* H     = (const float*)d_in[1];
  const float* theta = (const float*)d_in[2];
  const float* bias  = (const float*)d_in[3];

  // ws (bytes): xtT 2MB | p_he 16MB | heT 1MB | deg_e_part 256KB | Hbits 4MB
  char* ws = (char*)d_ws;
  unsigned short* xtT       = (unsigned short*)ws;
  float* p_he               = (float*)(ws + 2097152);
  unsigned short* heT       = (unsigned short*)(ws + 18874368);
  float* deg_e_part         = (float*)(ws + 19922944);
  unsigned long long* Hbits = (unsigned long long*)(ws + 20185088);

  k_transform<<<256, 256, 0, stream>>>(x, theta, xtT);
  k_edge<<<1024, 256, 0, stream>>>(xtT, H, p_he, deg_e_part, Hbits);
  k_henorm<<<512, 256, 0, stream>>>(p_he, deg_e_part, heT);
  k_node<<<1024, 256, 0, stream>>>(Hbits, heT, bias, (float*)d_out);
}

// Round 5
// 242.550 us; speedup vs baseline: 1.0668x; 1.0289x over previous
//
#include <hip/hip_runtime.h>

// B=4, N=4096, E=2048, C=64.  Consolidated best-of-session configuration:
//  k_transform: xtT[b][o][n] bf16 (2 MB)
//  k_edge:  ks=4 K-split (R0/R2 config, halves p_he round-trip vs ks=8).
//           p_he[ks] += xtT * H (cndmask fp32->bf16) AND Hbits word-major
//           via __ballot AND deg_e_part. ONLY reader of fp32 H (134 MB);
//           provably BW-bound (per-CU VALU ~530cy/kt vs mem ~6400cy/kt).
//  k_henorm: combine/deg_e -> heT bf16 (1 MB)
//  k_node:  R1's fused 64n x 32o variant (best fused k_node measured).
//           out = (H * heT)/deg_n + bias, full-E accumulation; A = Hbits
//           u64 expanded in regs, B = heT double-buffered global_load_lds;
//           deg_n via popcount; divide+bias in epilogue.
#define B_ 4
#define N_ 4096
#define E_ 2048

typedef __attribute__((ext_vector_type(8))) short short8;   // 8 bf16
typedef __attribute__((ext_vector_type(4))) float float4v;  // MFMA C/D

// round-to-nearest-even f32 -> bf16 bits
static __device__ __forceinline__ unsigned short f2bf(float f) {
  union { float f; unsigned int u; } v; v.f = f;
  unsigned int r = (v.u + 0x7FFFu + ((v.u >> 16) & 1u)) >> 16;
  return (unsigned short)r;
}

// expand 8 H-bits -> 8 bf16 values {0.0, 1.0}
static __device__ __forceinline__ short8 expand8(unsigned int by) {
  short8 r;
#pragma unroll
  for (int j = 0; j < 8; ++j)
    r[j] = (short)(((by >> j) & 1u) ? 0x3F80 : 0);
  return r;
}

static __device__ __forceinline__ void stage16(const void* g, void* l) {
  __builtin_amdgcn_global_load_lds(
      (const __attribute__((address_space(1))) unsigned int*)g,
      (__attribute__((address_space(3))) unsigned int*)l, 16, 0, 0);
}

// ---------------------------------------------------------------------------
// K1: xtT[b][o][n] = bf16( sum_k x[b][n][k] * theta[k][o] )   (transposed)
// ---------------------------------------------------------------------------
__global__ __launch_bounds__(256) void k_transform(
    const float* __restrict__ x, const float* __restrict__ theta,
    unsigned short* __restrict__ xtT) {
  __shared__ unsigned short ldsT[64][72];
  int t = threadIdx.x;
  int nt = blockIdx.x & 63, b = blockIdx.x >> 6;
  int n0 = nt * 64;
  int o = t & 63, nq = t >> 6;
#pragma unroll 4
  for (int i = 0; i < 16; ++i) {
    int n = n0 + nq * 16 + i;
    const float* xr = x + ((size_t)(b * N_ + n) << 6);
    float acc = 0.f;
#pragma unroll
    for (int k = 0; k < 64; ++k) acc += xr[k] * theta[k * 64 + o];
    ldsT[o][nq * 16 + i] = f2bf(acc);
  }
  __syncthreads();
  int orow = t >> 2, c = (t & 3) * 16;
  unsigned short* dst = xtT + ((size_t)(b * 64 + orow) << 12) + n0 + c;
  *(uint4*)dst = *(const uint4*)&ldsT[orow][c];
  *(uint4*)(dst + 8) = *(const uint4*)&ldsT[orow][c + 8];
}

// ---------------------------------------------------------------------------
// K2 (fused edge GEMM + bit-pack): for K-chunk ks (1024 n each, x4):
//   p_he[ks][b][o][e]    = sum_{n chunk} xtT[o][n] * H[n][e]
//   deg_e_part[ks][b][e] = sum_{n chunk} H[n][e]
//   Hbits[b][et][n chunk] = ballot-packed bits (word-major)
// grid 512 = ks(4) x et(32) x b(4); block 64o x 64e, BK=64, 16 iters.
// ---------------------------------------------------------------------------
__global__ __launch_bounds__(256) void k_edge(
    const unsigned short* __restrict__ xtT, const float* __restrict__ H,
    float* __restrict__ p_he, float* __restrict__ deg_e_part,
    unsigned long long* __restrict__ Hbits) {
  __shared__ unsigned short ldsA[4096];     // [o-row][k=n] 64x64, swizzled
  __shared__ unsigned short ldsB[64 * 72];  // [e-row][n] 64x72 padded
  __shared__ float ldsDe[64];
  __shared__ unsigned long long ldsW[1024];  // packed words for this n-chunk
  int t = threadIdx.x;
  int ks = blockIdx.x & 3, et = (blockIdx.x >> 2) & 31, b = blockIdx.x >> 7;
  int e0 = et * 64;
  int w = t >> 6, lane = t & 63, quad = lane >> 4, m15 = lane & 15;
  if (t < 64) ldsDe[t] = 0.f;

  int i0 = w * 128 + lane, i1 = i0 + 64;
  int row0 = i0 >> 3, cc0 = (i0 & 7) ^ (row0 & 7);
  int row1 = i1 >> 3, cc1 = (i1 & 7) ^ (row1 & 7);
  int gOff0 = row0 * 4096 + cc0 * 8;
  int gOff1 = row1 * 4096 + cc1 * 8;
  char* lA = (char*)ldsA; char* lB = (char*)ldsB;
  int lOff0 = i0 * 16, lOff1 = i1 * 16;

  const unsigned short* gA = xtT + ((size_t)b << 18) + ks * 1024;
  const float* gH = H + ((size_t)(b * N_ + ks * 1024 + w * 16)) * E_ + e0 + lane;

  int xr = m15 & 7;
  int aBase = (w * 16 + m15) * 128;
  int fs0 = (quad ^ xr) * 16, fs1 = ((4 + quad) ^ xr) * 16;
  int bw = lane * 144 + w * 32;

  float de = 0.f;
  float4v acc[4];
#pragma unroll
  for (int ct = 0; ct < 4; ++ct) acc[ct] = (float4v){0.f, 0.f, 0.f, 0.f};

  for (int kt = 0; kt < 16; ++kt) {
    float hv[16];
#pragma unroll
    for (int i = 0; i < 16; ++i) hv[i] = gH[(size_t)i * E_];
    // bit-pack: lane = e offset -> one 64-bit word per n-row
#pragma unroll
    for (int i = 0; i < 16; ++i) {
      unsigned long long m = __ballot(hv[i] != 0.0f);
      if (lane == 0) ldsW[kt * 64 + w * 16 + i] = m;
    }
#pragma unroll
    for (int i = 0; i < 16; ++i) de += hv[i];
    // H is exactly {0.0,1.0}: bf16 is a cndmask on the compare the ballot
    // already needs (f2bf RNE bit-math was ~5 VALU ops/element).
    short8 pa, pb;
#pragma unroll
    for (int i = 0; i < 8; ++i)
      pa[i] = (hv[i] != 0.0f) ? (short)0x3F80 : (short)0;
#pragma unroll
    for (int i = 0; i < 8; ++i)
      pb[i] = (hv[8 + i] != 0.0f) ? (short)0x3F80 : (short)0;
    *(short8*)(lB + bw) = pa;
    *(short8*)(lB + bw + 16) = pb;
    stage16(gA + gOff0, lA + lOff0);
    stage16(gA + gOff1, lA + lOff1);
    __syncthreads();
#pragma unroll
    for (int s = 0; s < 2; ++s) {
      int fo = s ? fs1 : fs0;
      short8 a = *(const short8*)(lA + aBase + fo);
#pragma unroll
      for (int ct = 0; ct < 4; ++ct) {
        short8 bb =
            *(const short8*)(lB + (ct * 16 + m15) * 144 + s * 64 + quad * 16);
        acc[ct] = __builtin_amdgcn_mfma_f32_16x16x32_bf16(a, bb, acc[ct], 0, 0, 0);
      }
    }
    __syncthreads();
    gA += 64;
    gH += (size_t)64 * E_;
  }
  atomicAdd(&ldsDe[lane], de);
  __syncthreads();
  if (t < 64) deg_e_part[ks * (B_ * E_) + b * E_ + e0 + t] = ldsDe[t];
  // coalesced Hbits write: [b][et][n], n-chunk = ks*1024..+1024 (8 KB/block)
  unsigned long long* wdst =
      Hbits + (((size_t)(b * 32 + et)) << 12) + ks * 1024 + t * 4;
  wdst[0] = ldsW[t * 4 + 0];
  wdst[1] = ldsW[t * 4 + 1];
  wdst[2] = ldsW[t * 4 + 2];
  wdst[3] = ldsW[t * 4 + 3];
  float* dst = p_he + (size_t)ks * (B_ * 64 * E_);
#pragma unroll
  for (int ct = 0; ct < 4; ++ct)
#pragma unroll
    for (int r = 0; r < 4; ++r) {
      int oo = w * 16 + quad * 4 + r;
      dst[((size_t)(b * 64 + oo)) * E_ + e0 + ct * 16 + m15] = acc[ct][r];
    }
}

// ---------------------------------------------------------------------------
// K3: heT[b][o][e] = bf16( (sum_ks p_he[ks]) / (sum_ks deg_e_part[ks]) )
// ---------------------------------------------------------------------------
__global__ __launch_bounds__(256) void k_henorm(
    const float* __restrict__ p_he, const float* __restrict__ deg_e_part,
    unsigned short* __restrict__ heT) {
  int idx = (blockIdx.x * 256 + threadIdx.x) * 4;  // over B*64*E = 524288
  int e = idx & (E_ - 1);
  int b = idx >> 17;
  float4 s = *(const float4*)(p_he + idx);
  float4 d = *(const float4*)(deg_e_part + b * E_ + e);
#pragma unroll
  for (int k = 1; k < 4; ++k) {
    float4 sk = *(const float4*)(p_he + (size_t)k * (B_ * 64 * E_) + idx);
    float4 dk = *(const float4*)(deg_e_part + k * (B_ * E_) + b * E_ + e);
    s.x += sk.x; s.y += sk.y; s.z += sk.z; s.w += sk.w;
    d.x += dk.x; d.y += dk.y; d.z += dk.z; d.w += dk.w;
  }
  unsigned int lo = (unsigned int)f2bf(s.x / d.x) |
                    ((unsigned int)f2bf(s.y / d.y) << 16);
  unsigned int hi = (unsigned int)f2bf(s.z / d.z) |
                    ((unsigned int)f2bf(s.w / d.w) << 16);
  uint2 u; u.x = lo; u.y = hi;
  *(uint2*)(heT + idx) = u;
}

// ---------------------------------------------------------------------------
// K4 (fused node GEMM + normalize + bias):
//   out[b][n][o] = (sum_e H[n][e]*heT[o][e]) / deg_n[n] + bias[o]
// grid 512 = mt(64) x ot(2) x b(4); tile 64n x 32o, full E (32 k-steps).
// A = Hbits[b][wd][n] u64 (L2-hot) prefetched 1 word ahead;
// B = heT staged via global_load_lds, 2-deep double-buffered.
// deg_n via popcount of the same words; divide+bias fused in epilogue.
// ---------------------------------------------------------------------------
__global__ __launch_bounds__(256) void k_node(
    const unsigned long long* __restrict__ Hbits,
    const unsigned short* __restrict__ heT,
    const float* __restrict__ bias, float* __restrict__ out) {
  __shared__ unsigned short ldsB[2][2048];  // [buf][32 o x 64 e] swizzled
  int t = threadIdx.x;
  int mt = blockIdx.x & 63, ot = (blockIdx.x >> 6) & 1, b = blockIdx.x >> 7;
  int n0 = mt * 64, o0 = ot * 32;
  int w = t >> 6, lane = t & 63, quad = lane >> 4, m15 = lane & 15;

  // staging: 32 o-rows x 64 e (128 B/row = 8 segs), 1 stage16/thread/step
  int row = t >> 3, seg = t & 7;
  int cc = seg ^ (row & 7);  // pre-swizzled global source, linear LDS dest
  const unsigned short* gB =
      heT + (((size_t)(b * 64 + o0 + row)) << 11) + cc * 8;
  char* lB = (char*)ldsB;
  int lOff = t * 16;

  int nl = n0 + w * 16 + m15;
  const unsigned long long* gAb = Hbits + (((size_t)b * 32) << 12) + nl;

  int xr = m15 & 7;
  int fs0 = (quad ^ xr) * 16, fs1 = ((4 + quad) ^ xr) * 16;

  float4v acc[2];
  acc[0] = (float4v){0.f, 0.f, 0.f, 0.f};
  acc[1] = (float4v){0.f, 0.f, 0.f, 0.f};

  unsigned int dcnt = 0;
  unsigned long long ua = gAb[0];
  stage16(gB, lB + lOff);  // buf0 <- e-chunk 0
  __syncthreads();

  for (int kt = 0; kt < 32; ++kt) {
    int cur = kt & 1;
    if (kt < 31) {
      stage16(gB + (kt + 1) * 64, lB + (cur ^ 1) * 4096 + lOff);
    }
    unsigned long long va = 0;
    if (kt < 31) va = gAb[(size_t)(kt + 1) << 12];  // prefetch next word
    dcnt += (unsigned int)__popcll(ua);
#pragma unroll
    for (int s = 0; s < 2; ++s) {
      int fo = s ? fs1 : fs0;
      short8 a = expand8((unsigned int)(ua >> ((s * 4 + quad) << 3)) & 0xFFu);
#pragma unroll
      for (int ct = 0; ct < 2; ++ct) {
        short8 bb =
            *(const short8*)(lB + cur * 4096 + (ct * 16 + m15) * 128 + fo);
        acc[ct] = __builtin_amdgcn_mfma_f32_16x16x32_bf16(a, bb, acc[ct], 0, 0, 0);
      }
    }
    ua = va;
    __syncthreads();  // drains own vmcnt (stage + va); buf swap safe
  }

  float dn = (float)dcnt;  // same for all quads of a given (w, m15)
  float bv0 = bias[o0 + m15];
  float bv1 = bias[o0 + 16 + m15];
  float* dst = out + (((size_t)(b * N_ + n0)) << 6) + o0;
#pragma unroll
  for (int r = 0; r < 4; ++r) {
    float inv = 1.0f / __shfl(dn, quad * 4 + r, 16);
    int rr = w * 16 + quad * 4 + r;
    dst[((size_t)rr << 6) + m15] = acc[0][r] * inv + bv0;
    dst[((size_t)rr << 6) + 16 + m15] = acc[1][r] * inv + bv1;
  }
}

extern "C" void kernel_launch(void* const* d_in, const int* in_sizes, int n_in,
                              void* d_out, int out_size, void* d_ws, size_t ws_size,
                              hipStream_t stream) {
  const float* x     = (const float*)d_in[0];
  const float* H     = (const float*)d_in[1];
  const float* theta = (const float*)d_in[2];
  const float* bias  = (const float*)d_in[3];

  // ws (bytes): xtT 2MB | p_he 8MB | heT 1MB | deg_e_part 128KB | Hbits 4MB
  //             (~15.1 MB total)
  char* ws = (char*)d_ws;
  unsigned short* xtT       = (unsigned short*)ws;
  float* p_he               = (float*)(ws + 2097152);
  unsigned short* heT       = (unsigned short*)(ws + 10485760);
  float* deg_e_part         = (float*)(ws + 11534336);
  unsigned long long* Hbits = (unsigned long long*)(ws + 11665408);

  k_transform<<<256, 256, 0, stream>>>(x, theta, xtT);
  k_edge<<<512, 256, 0, stream>>>(xtT, H, p_he, deg_e_part, Hbits);
  k_henorm<<<512, 256, 0, stream>>>(p_he, deg_e_part, heT);
  k_node<<<512, 256, 0, stream>>>(Hbits, heT, bias, (float*)d_out);
}